// Round 6
// baseline (462.862 us; speedup 1.0000x reference)
//
#include <hip/hip_runtime.h>

typedef __attribute__((ext_vector_type(8))) short short8;
typedef __attribute__((ext_vector_type(16))) float f32x16;

constexpr int B_ = 32, C_ = 512, F_ = 96, P_ = 512;
constexpr int NTH = 576;           // 9 waves: wave = (gate, f-tile)
constexpr int GRID = 512;          // 1 position per block -> exactly 2 blocks/CU
constexpr size_t OUT_HALF = (size_t)B_ * P_ * F_;

// ---- workspace layout (bytes) ----
constexpr size_t WS_U  = 0;                        // [27 tap][3 g][96 f][52 u32] bf16 pairs (rows 208B)
constexpr size_t WS_U_SZ = 27ull * 3 * 96 * 52 * 4;
constexpr size_t WS_H  = WS_U + WS_U_SZ;           // [32 b][512 p][96 ci] bf16 (rows 192B)
constexpr size_t WS_H_SZ = 32ull * 512 * 96 * 2;
constexpr size_t WS_X  = WS_H + WS_H_SZ;           // [32 b][512 c] bf16
constexpr size_t WS_X_SZ = 32ull * 512 * 2;
constexpr size_t WS_END = WS_X + WS_X_SZ;          // 4,795,904

// ---- dynamic LDS layout (bytes) ----
constexpr int X_OFF    = 0;                 // x bf16 [32 b][1040B]
constexpr int X_STRIDE = 1040;
constexpr int H_OFF    = 33280;             // h tap slab, 2 bufs x [32 b][208B]
constexpr int H_BUF    = 32 * 208;          // 6656
constexpr int LDS_TOTAL = H_OFF + 2 * H_BUF;    // 46,592
// epilogue reuses sm[0..36864) as pre[3g][32b][96f] f32 (x/h dead by then)

__device__ __forceinline__ unsigned short f2bf(float v) {
    unsigned int u = __float_as_uint(v);
    unsigned int r = (u + 0x7FFFu + ((u >> 16) & 1u)) >> 16;  // RNE
    return (unsigned short)r;
}
__device__ __forceinline__ unsigned pack2bf(float a, float b) {
    return (unsigned)f2bf(a) | ((unsigned)f2bf(b) << 16);
}
__device__ __forceinline__ float bf2f(unsigned short v) {
    return __uint_as_float(((unsigned int)v) << 16);
}

// ================= prep kernels (validated r3/r4/r5) =================
__global__ __launch_bounds__(256) void prep_u(const float* __restrict__ Uf,
                                              const float* __restrict__ Ui,
                                              const float* __restrict__ Us,
                                              unsigned char* __restrict__ wsb) {
    __shared__ float s32[96 * 97];
    const int t = blockIdx.x / 3, g = blockIdx.x % 3;
    const float* U = (g == 0 ? Uf : (g == 1 ? Ui : Us)) + (size_t)t * 9216;
    const int tid = threadIdx.x;
    #pragma unroll
    for (int j = 0; j < 36; ++j) {
        int idx = j * 256 + tid;
        int ci = idx / 96, f = idx % 96;
        s32[ci * 97 + f] = U[idx];
    }
    __syncthreads();
    unsigned* dst = (unsigned*)(wsb + WS_U) + (size_t)(t * 3 + g) * 4992;
    #pragma unroll
    for (int j = 0; j < 20; ++j) {
        int o = j * 256 + tid;
        if (o < 4992) {
            int f = o / 52, qq = o % 52;
            unsigned pk = 0u;
            if (qq < 48) pk = pack2bf(s32[(2 * qq) * 97 + f], s32[(2 * qq + 1) * 97 + f]);
            dst[o] = pk;
        }
    }
}

__global__ __launch_bounds__(256) void prep_hx(const float* __restrict__ h_t,
                                               const float* __restrict__ x,
                                               unsigned char* __restrict__ wsb) {
    unsigned* wh = (unsigned*)(wsb + WS_H);
    unsigned* wx = (unsigned*)(wsb + WS_X);
    const int tid = threadIdx.x;
    #pragma unroll
    for (int j = 0; j < 4; ++j) {
        size_t u = (size_t)blockIdx.x * 1024 + j * 256 + tid;
        if (u < 786432) {
            float2 v = *(const float2*)(h_t + 2 * u);
            wh[u] = pack2bf(v.x, v.y);
        } else if (u < 794624) {
            size_t v_ = u - 786432;
            float2 v = *(const float2*)(x + 2 * v_);
            wx[v_] = pack2bf(v.x, v.y);
        }
    }
}

// ================= main fused kernel =================
// launch_bounds (576,5): VGPR cap 102 -> no spill (r5's (.,7) cap forced 650MB scratch),
// and guarantees >= 2 blocks/CU (grid gives exactly 2).
__global__ __launch_bounds__(NTH, 5) void lstm3d_main(
    const float* __restrict__ Wf, const float* __restrict__ Wi, const float* __restrict__ Ws,
    const float* __restrict__ s_t,
    const float* __restrict__ bfp, const float* __restrict__ bip, const float* __restrict__ bsp,
    const unsigned char* __restrict__ wsb, float* __restrict__ out)
{
    extern __shared__ char sm[];
    const int tid  = threadIdx.x;
    const int lane = tid & 63;
    const int wv   = tid >> 6;          // 0..8
    const int g    = wv / 3;            // gate 0..2
    const int n    = wv % 3;            // f-tile (32 wide)
    const int l31  = lane & 31, l5 = lane >> 5;

    const int p  = blockIdx.x;
    const int dd = p >> 6, hh = (p >> 3) & 7, ww = p & 7;

    const unsigned char* wh8 = wsb + WS_H;
    const unsigned char* wu8 = wsb + WS_U;
    const unsigned char* wx8 = wsb + WS_X;

    f32x16 acc;
    #pragma unroll
    for (int r = 0; r < 16; ++r) acc[r] = 0.f;

    // ---- stage x once: ws bf16 [32][1024B] -> LDS [32][1040B] ----
    #pragma unroll
    for (int i0 = 0; i0 < 4; ++i0) {
        int i = i0 * NTH + tid;
        if (i < 2048) {
            int row = i >> 6, gq = i & 63;
            *(uint4*)(sm + X_OFF + row * X_STRIDE + gq * 16) =
                *(const uint4*)(wx8 + row * 1024 + gq * 16);
        }
    }
    __syncthreads();

    // ================= projection phase: ZERO barriers, 3-deep prefetch =================
    // B-frag lane l: f = n*32+l31 (col), k = ks*16 + l5*8 + j. Direct global->reg->bf16.
    auto do_proj = [&]() {
        const float* Wg = (g == 0) ? Wf : ((g == 1) ? Wi : Ws);
        const float* wbase = Wg + (size_t)p * C_ * F_ + n * 32 + l31;

        float wlA[8], wlB[8], wlC[8];
        auto issue = [&](int ks, float (&wl)[8]) {
            const float* q = wbase + (size_t)(ks * 16 + l5 * 8) * 96;
            #pragma unroll
            for (int j = 0; j < 8; ++j) wl[j] = q[(size_t)j * 96];
        };
        auto step = [&](int ks, float (&wl)[8]) {
            short8 a = *(const short8*)(sm + X_OFF + l31 * X_STRIDE + ks * 32 + l5 * 16);
            uint4 bu;
            bu.x = pack2bf(wl[0], wl[1]);
            bu.y = pack2bf(wl[2], wl[3]);
            bu.z = pack2bf(wl[4], wl[5]);
            bu.w = pack2bf(wl[6], wl[7]);
            if (ks + 3 < 32) issue(ks + 3, wl);   // refill AFTER consuming; no barrier follows
            acc = __builtin_amdgcn_mfma_f32_32x32x16_bf16(a, __builtin_bit_cast(short8, bu),
                                                          acc, 0, 0, 0);
        };

        issue(0, wlA);
        issue(1, wlB);
        issue(2, wlC);
        for (int k3 = 0; k3 < 10; ++k3) {
            step(3 * k3,     wlA);
            step(3 * k3 + 1, wlB);
            step(3 * k3 + 2, wlC);
        }
        step(30, wlA);
        step(31, wlB);
    };

    // ================= conv phase: ONE barrier per tap =================
    auto do_conv = [&]() {
        const unsigned char* ubrow = wu8 + (size_t)(g * 96 + n * 32 + l31) * 208;
        const int hb = tid / 12, hq = tid % 12;

        auto tapok = [&](int kt, int& np) -> bool {
            int kd = kt / 9, kh = (kt / 3) % 3, kw = kt % 3;
            int nd = dd + kd - 1, nh = hh + kh - 1, nw = ww + kw - 1;
            np = nd * 64 + nh * 8 + nw;
            return ((unsigned)nd < 8u) && ((unsigned)nh < 8u) && ((unsigned)nw < 8u);
        };

        int kt = 0, np = 0;
        while (kt < 27 && !tapok(kt, np)) ++kt;

        // prologue: stage first active tap into buf0
        if (tid < 384) {
            uint4 hv = *(const uint4*)(wh8 + (size_t)hb * 98304 + np * 192 + hq * 16);
            *(uint4*)(sm + H_OFF + hb * 208 + hq * 16) = hv;
        }
        __syncthreads();

        int buf = 0;
        while (kt < 27) {
            int ktn = kt + 1, npn = 0;
            while (ktn < 27 && !tapok(ktn, npn)) ++ktn;
            const bool havenext = (ktn < 27);

            // issue next-slab load + this-tap U fragments right after the barrier
            uint4 hvn;
            if (havenext && tid < 384)
                hvn = *(const uint4*)(wh8 + (size_t)hb * 98304 + npn * 192 + hq * 16);
            uint4 bb[6];
            const unsigned char* ub = ubrow + (size_t)kt * 59904;
            #pragma unroll
            for (int ks = 0; ks < 6; ++ks)
                bb[ks] = *(const uint4*)(ub + ks * 32 + l5 * 16);

            const char* shb = sm + H_OFF + buf * H_BUF;
            #pragma unroll
            for (int ks = 0; ks < 6; ++ks) {
                short8 a = *(const short8*)(shb + l31 * 208 + ks * 32 + l5 * 16);
                short8 b = __builtin_bit_cast(short8, bb[ks]);
                acc = __builtin_amdgcn_mfma_f32_32x32x16_bf16(a, b, acc, 0, 0, 0);
            }

            if (havenext && tid < 384)
                *(uint4*)(sm + H_OFF + (buf ^ 1) * H_BUF + hb * 208 + hq * 16) = hvn;
            __syncthreads();
            buf ^= 1;
            kt = ktn;
        }
    };

    // stagger: a CU's two resident blocks (bid, bid+8 under XCD round-robin) run
    // opposite phase orders, so one streams HBM while the other does L2+MFMA.
    if ((blockIdx.x >> 3) & 1) { do_proj(); do_conv(); }
    else                       { do_conv(); do_proj(); }

    // ================= merge + epilogue =================
    __syncthreads();
    float* pre = (float*)sm;                       // [3 g][32 b][96 f] f32 = 36,864B
    #pragma unroll
    for (int r = 0; r < 16; ++r) {
        const int b = (r & 3) + 8 * (r >> 2) + 4 * l5;   // verified 32x32 C/D row mapping
        pre[(g * 32 + b) * 96 + n * 32 + l31] = acc[r];
    }
    __syncthreads();

    #pragma unroll
    for (int j = 0; j < 6; ++j) {
        const int i = j * NTH + tid;
        if (i < 3072) {
            const int b = i / 96, f = i % 96;
            const float gfv = pre[(0 * 32 + b) * 96 + f] + bfp[f];
            const float giv = pre[(1 * 32 + b) * 96 + f] + bip[f];
            const float gsv = pre[(2 * 32 + b) * 96 + f] + bsp[f];
            const size_t idx = ((size_t)b * 512 + p) * 96 + f;
            const float fg = fminf(fmaxf(0.2f * gfv + 0.5f, 0.f), 1.f);
            const float ig = fminf(fmaxf(0.2f * giv + 0.5f, 0.f), 1.f);
            const float sv = fg * s_t[idx] + ig * tanhf(gsv);
            out[idx] = tanhf(sv);
            out[OUT_HALF + idx] = sv;
        }
    }
}

// ================= fp32 fallback (r2 kernel, used if ws too small) =================
constexpr int FNTH = 384;
constexpr int FBPG = 8;
__global__ __launch_bounds__(FNTH, 3) void lstm3d_fused(
    const float* __restrict__ x, const float* __restrict__ h_t, const float* __restrict__ s_t,
    const float* __restrict__ Wf, const float* __restrict__ Wi, const float* __restrict__ Ws,
    const float* __restrict__ Uf, const float* __restrict__ Ui, const float* __restrict__ Us,
    const float* __restrict__ bf, const float* __restrict__ bi, const float* __restrict__ bs,
    float* __restrict__ out)
{
    __shared__ __align__(16) unsigned char lds_raw[B_*C_*2 + B_*F_*4];
    unsigned short* s_in = (unsigned short*)lds_raw;
    float*          s_h  = (float*)(lds_raw + B_*C_*2);
    const int p = blockIdx.x, d = p >> 6, hh = (p >> 3) & 7, ww = p & 7;
    const int tid = threadIdx.x, f = tid % F_, bg = tid / F_, b0 = bg * FBPG;
    {
        const float4* x4 = (const float4*)x;
        ushort4* s4 = (ushort4*)s_in;
        for (int i = tid; i < B_ * C_ / 4; i += FNTH) {
            float4 v = x4[i];
            ushort4 u; u.x = f2bf(v.x); u.y = f2bf(v.y); u.z = f2bf(v.z); u.w = f2bf(v.w);
            s4[i] = u;
        }
    }
    __syncthreads();
    const size_t wbase = (size_t)p * C_ * F_;
    const float* Wfp = Wf + wbase; const float* Wip = Wi + wbase; const float* Wsp = Ws + wbase;
    float af[FBPG], ai[FBPG], as_[FBPG];
    #pragma unroll
    for (int j = 0; j < FBPG; ++j) { af[j] = 0.f; ai[j] = 0.f; as_[j] = 0.f; }
    for (int c = 0; c < C_; c += 4) {
        float xs[FBPG][4];
        #pragma unroll
        for (int j = 0; j < FBPG; ++j) {
            ushort4 uv = *(const ushort4*)&s_in[(b0 + j) * C_ + c];
            xs[j][0] = bf2f(uv.x); xs[j][1] = bf2f(uv.y); xs[j][2] = bf2f(uv.z); xs[j][3] = bf2f(uv.w);
        }
        #pragma unroll
        for (int cc = 0; cc < 4; ++cc) {
            const float wfv = Wfp[(c + cc) * F_ + f], wiv = Wip[(c + cc) * F_ + f], wsv = Wsp[(c + cc) * F_ + f];
            #pragma unroll
            for (int j = 0; j < FBPG; ++j) {
                af[j] = fmaf(xs[j][cc], wfv, af[j]); ai[j] = fmaf(xs[j][cc], wiv, ai[j]); as_[j] = fmaf(xs[j][cc], wsv, as_[j]);
            }
        }
    }
    float cf[FBPG], cig[FBPG], cs[FBPG];
    #pragma unroll
    for (int j = 0; j < FBPG; ++j) { cf[j] = 0.f; cig[j] = 0.f; cs[j] = 0.f; }
    for (int kd = 0; kd < 3; ++kd) {
        const int nd = d + kd - 1; if ((unsigned)nd >= 8u) continue;
        for (int kh = 0; kh < 3; ++kh) {
            const int nh = hh + kh - 1; if ((unsigned)nh >= 8u) continue;
            for (int kw = 0; kw < 3; ++kw) {
                const int nw = ww + kw - 1; if ((unsigned)nw >= 8u) continue;
                const int np = (nd << 6) + (nh << 3) + nw, k = (kd * 3 + kh) * 3 + kw;
                __syncthreads();
                {
                    const float4* h4 = (const float4*)h_t; float4* s4 = (float4*)s_h;
                    for (int i = tid; i < B_ * F_ / 4; i += FNTH) {
                        const int b2 = i / (F_ / 4), r = i % (F_ / 4);
                        s4[i] = h4[(size_t)(b2 * P_ + np) * (F_ / 4) + r];
                    }
                }
                __syncthreads();
                const float* Ufk = Uf + (size_t)k * F_ * F_; const float* Uik = Ui + (size_t)k * F_ * F_; const float* Usk = Us + (size_t)k * F_ * F_;
                for (int ci = 0; ci < F_; ci += 4) {
                    float hs[FBPG][4];
                    #pragma unroll
                    for (int j = 0; j < FBPG; ++j) {
                        float4 t = *(const float4*)&s_h[(b0 + j) * F_ + ci];
                        hs[j][0] = t.x; hs[j][1] = t.y; hs[j][2] = t.z; hs[j][3] = t.w;
                    }
                    #pragma unroll
                    for (int cc = 0; cc < 4; ++cc) {
                        const float ufv = Ufk[(ci + cc) * F_ + f], uiv = Uik[(ci + cc) * F_ + f], usv = Usk[(ci + cc) * F_ + f];
                        #pragma unroll
                        for (int j = 0; j < FBPG; ++j) {
                            cf[j] = fmaf(hs[j][cc], ufv, cf[j]); cig[j] = fmaf(hs[j][cc], uiv, cig[j]); cs[j] = fmaf(hs[j][cc], usv, cs[j]);
                        }
                    }
                }
            }
        }
    }
    const float bfv = bf[f], biv = bi[f], bsv = bs[f];
    #pragma unroll
    for (int j = 0; j < FBPG; ++j) {
        const size_t idx = (size_t)((b0 + j) * P_ + p) * F_ + f;
        const float gf = af[j] + cf[j] + bfv, gi = ai[j] + cig[j] + biv, gs = as_[j] + cs[j] + bsv;
        const float fg = fminf(fmaxf(0.2f * gf + 0.5f, 0.f), 1.f);
        const float ig = fminf(fmaxf(0.2f * gi + 0.5f, 0.f), 1.f);
        const float sv = fg * s_t[idx] + ig * tanhf(gs);
        out[idx] = tanhf(sv);
        out[OUT_HALF + idx] = sv;
    }
}

extern "C" void kernel_launch(void* const* d_in, const int* in_sizes, int n_in,
                              void* d_out, int out_size, void* d_ws, size_t ws_size,
                              hipStream_t stream) {
    const float* x   = (const float*)d_in[0];
    const float* h_t = (const float*)d_in[1];
    const float* s_t = (const float*)d_in[2];
    const float* Wf  = (const float*)d_in[3];
    const float* Wi  = (const float*)d_in[4];
    const float* Ws  = (const float*)d_in[5];
    const float* Uf  = (const float*)d_in[6];
    const float* Ui  = (const float*)d_in[7];
    const float* Us  = (const float*)d_in[8];
    const float* bf  = (const float*)d_in[9];
    const float* bi  = (const float*)d_in[10];
    const float* bs  = (const float*)d_in[11];
    float* out = (float*)d_out;

    if (ws_size >= WS_END) {
        (void)hipFuncSetAttribute(reinterpret_cast<const void*>(lstm3d_main),
                                  hipFuncAttributeMaxDynamicSharedMemorySize, LDS_TOTAL);
        unsigned char* wsb = (unsigned char*)d_ws;
        hipLaunchKernelGGL(prep_u, dim3(81), dim3(256), 0, stream, Uf, Ui, Us, wsb);
        hipLaunchKernelGGL(prep_hx, dim3(776), dim3(256), 0, stream, h_t, x, wsb);
        hipLaunchKernelGGL(lstm3d_main, dim3(GRID), dim3(NTH), LDS_TOTAL, stream,
                           Wf, Wi, Ws, s_t, bf, bi, bs, wsb, out);
    } else {
        hipLaunchKernelGGL(lstm3d_fused, dim3(P_), dim3(FNTH), 0, stream,
                           x, h_t, s_t, Wf, Wi, Ws, Uf, Ui, Us, bf, bi, bs, out);
    }
}

// Round 7
// 139.458 us; speedup vs baseline: 3.3190x; 3.3190x over previous
//
#include <hip/hip_runtime.h>

typedef __attribute__((ext_vector_type(8))) short short8;
typedef __attribute__((ext_vector_type(16))) float f32x16;

constexpr int B_ = 32, C_ = 512, F_ = 96, P_ = 512;
constexpr int NTH = 576;           // 9 waves: wave = (gate, f-tile)
constexpr size_t OUT_HALF = (size_t)B_ * P_ * F_;

// ---- workspace layout (bytes) ----
constexpr size_t WS_U  = 0;                        // [27 tap][3 g][96 f][52 u32] bf16 pairs (rows 208B)
constexpr size_t WS_U_SZ = 27ull * 3 * 96 * 52 * 4;
constexpr size_t WS_H  = WS_U + WS_U_SZ;           // [32 b][512 p][96 ci] bf16 (rows 192B)
constexpr size_t WS_H_SZ = 32ull * 512 * 96 * 2;
constexpr size_t WS_X  = WS_H + WS_H_SZ;           // [32 b][512 c] bf16
constexpr size_t WS_X_SZ = 32ull * 512 * 2;
constexpr size_t WS_PART = WS_X + WS_X_SZ;         // 4,795,904 (== old WS_END)
constexpr size_t WS_PART_SZ = 512ull * 3 * 32 * 96 * 4;  // 18,874,368: conv partials [p][3g][32b][96f] f32
constexpr size_t WS_END = WS_PART + WS_PART_SZ;    // 23,670,272

__device__ __forceinline__ unsigned short f2bf(float v) {
    unsigned int u = __float_as_uint(v);
    unsigned int r = (u + 0x7FFFu + ((u >> 16) & 1u)) >> 16;  // RNE
    return (unsigned short)r;
}
__device__ __forceinline__ unsigned pack2bf(float a, float b) {
    return (unsigned)f2bf(a) | ((unsigned)f2bf(b) << 16);
}
__device__ __forceinline__ float bf2f(unsigned short v) {
    return __uint_as_float(((unsigned int)v) << 16);
}
__device__ __forceinline__ void gload16(const void* g, void* l) {
    __builtin_amdgcn_global_load_lds(
        (const __attribute__((address_space(1))) unsigned int*)g,
        (__attribute__((address_space(3))) unsigned int*)l, 16, 0, 0);
}

// ================= prep kernels (validated r3-r6) =================
__global__ __launch_bounds__(256) void prep_u(const float* __restrict__ Uf,
                                              const float* __restrict__ Ui,
                                              const float* __restrict__ Us,
                                              unsigned char* __restrict__ wsb) {
    __shared__ float s32[96 * 97];
    const int t = blockIdx.x / 3, g = blockIdx.x % 3;
    const float* U = (g == 0 ? Uf : (g == 1 ? Ui : Us)) + (size_t)t * 9216;
    const int tid = threadIdx.x;
    #pragma unroll
    for (int j = 0; j < 36; ++j) {
        int idx = j * 256 + tid;
        int ci = idx / 96, f = idx % 96;
        s32[ci * 97 + f] = U[idx];
    }
    __syncthreads();
    unsigned* dst = (unsigned*)(wsb + WS_U) + (size_t)(t * 3 + g) * 4992;
    #pragma unroll
    for (int j = 0; j < 20; ++j) {
        int o = j * 256 + tid;
        if (o < 4992) {
            int f = o / 52, qq = o % 52;
            unsigned pk = 0u;
            if (qq < 48) pk = pack2bf(s32[(2 * qq) * 97 + f], s32[(2 * qq + 1) * 97 + f]);
            dst[o] = pk;
        }
    }
}

__global__ __launch_bounds__(256) void prep_hx(const float* __restrict__ h_t,
                                               const float* __restrict__ x,
                                               unsigned char* __restrict__ wsb) {
    unsigned* wh = (unsigned*)(wsb + WS_H);
    unsigned* wx = (unsigned*)(wsb + WS_X);
    const int tid = threadIdx.x;
    #pragma unroll
    for (int j = 0; j < 4; ++j) {
        size_t u = (size_t)blockIdx.x * 1024 + j * 256 + tid;
        if (u < 786432) {
            float2 v = *(const float2*)(h_t + 2 * u);
            wh[u] = pack2bf(v.x, v.y);
        } else if (u < 794624) {
            size_t v_ = u - 786432;
            float2 v = *(const float2*)(x + 2 * v_);
            wx[v_] = pack2bf(v.x, v.y);
        }
    }
}

// ================= kernel 1: conv -> partial gates in ws =================
// LDS: pre [3g][32b][96f] f32 (36,864) + h double-buf 2 x [32][208B] (13,312) = 50,176
__global__ __launch_bounds__(NTH, 4) void lstm3d_conv(unsigned char* __restrict__ wsb) {
    __shared__ __align__(16) char smc[36864 + 2 * 6656];
    const int tid  = threadIdx.x;
    const int lane = tid & 63;
    const int wv   = tid >> 6;
    const int g    = wv / 3;
    const int n    = wv % 3;
    const int l31  = lane & 31, l5 = lane >> 5;

    const int p  = blockIdx.x;
    const int dd = p >> 6, hh = (p >> 3) & 7, ww = p & 7;

    const unsigned char* wh8 = wsb + WS_H;
    const unsigned char* wu8 = wsb + WS_U;

    f32x16 acc;
    #pragma unroll
    for (int r = 0; r < 16; ++r) acc[r] = 0.f;

    const unsigned char* ubrow = wu8 + (size_t)(g * 96 + n * 32 + l31) * 208;
    const int hb = tid / 12, hq = tid % 12;

    auto tapok = [&](int kt, int& np) -> bool {
        int kd = kt / 9, kh = (kt / 3) % 3, kw = kt % 3;
        int nd = dd + kd - 1, nh = hh + kh - 1, nw = ww + kw - 1;
        np = nd * 64 + nh * 8 + nw;
        return ((unsigned)nd < 8u) && ((unsigned)nh < 8u) && ((unsigned)nw < 8u);
    };

    int kt = 0, np = 0;
    while (kt < 27 && !tapok(kt, np)) ++kt;

    if (tid < 384) {   // prologue: stage first active tap into buf0
        uint4 hv = *(const uint4*)(wh8 + (size_t)hb * 98304 + np * 192 + hq * 16);
        *(uint4*)(smc + 36864 + hb * 208 + hq * 16) = hv;
    }
    __syncthreads();

    int buf = 0;
    while (kt < 27) {
        int ktn = kt + 1, npn = 0;
        while (ktn < 27 && !tapok(ktn, npn)) ++ktn;
        const bool havenext = (ktn < 27);

        uint4 hvn;
        if (havenext && tid < 384)
            hvn = *(const uint4*)(wh8 + (size_t)hb * 98304 + npn * 192 + hq * 16);
        uint4 bb[6];
        const unsigned char* ub = ubrow + (size_t)kt * 59904;
        #pragma unroll
        for (int ks = 0; ks < 6; ++ks)
            bb[ks] = *(const uint4*)(ub + ks * 32 + l5 * 16);

        const char* shb = smc + 36864 + buf * 6656;
        #pragma unroll
        for (int ks = 0; ks < 6; ++ks) {
            short8 a = *(const short8*)(shb + l31 * 208 + ks * 32 + l5 * 16);
            short8 b = __builtin_bit_cast(short8, bb[ks]);
            acc = __builtin_amdgcn_mfma_f32_32x32x16_bf16(a, b, acc, 0, 0, 0);
        }

        if (havenext && tid < 384)
            *(uint4*)(smc + 36864 + (buf ^ 1) * 6656 + hb * 208 + hq * 16) = hvn;
        __syncthreads();
        buf ^= 1;
        kt = ktn;
    }

    // merge to pre, then coalesced store of partials
    float* pre = (float*)smc;
    #pragma unroll
    for (int r = 0; r < 16; ++r) {
        const int b = (r & 3) + 8 * (r >> 2) + 4 * l5;   // verified 32x32 C/D row mapping
        pre[(g * 32 + b) * 96 + n * 32 + l31] = acc[r];
    }
    __syncthreads();

    float4* dst = (float4*)(wsb + WS_PART + (size_t)p * 36864);
    const float4* src = (const float4*)pre;
    #pragma unroll
    for (int j = 0; j < 4; ++j) {
        int i = j * NTH + tid;          // 2304 float4 = 4*576 exactly
        dst[i] = src[i];
    }
}

// ================= kernel 2: projection (gload_lds 2-phase) + epilogue =================
constexpr int PJ_X    = 0;                  // x bf16 [32][1040B] = 33,280
constexpr int PJ_STG  = 33280;              // W fp32 stage: 2 bufs x [3g][16c][96f] = 2 x 18,432
constexpr int PJ_SBUF = 18432;
constexpr int PJ_LDS  = PJ_STG + 2 * PJ_SBUF;   // 70,144 -> 2 blocks/CU

__global__ __launch_bounds__(NTH, 4) void lstm3d_proj(
    const float* __restrict__ Wf, const float* __restrict__ Wi, const float* __restrict__ Ws,
    const float* __restrict__ s_t,
    const float* __restrict__ bfp, const float* __restrict__ bip, const float* __restrict__ bsp,
    const unsigned char* __restrict__ wsb, float* __restrict__ out)
{
    extern __shared__ char sm[];
    const int tid  = threadIdx.x;
    const int lane = tid & 63;
    const int wv   = tid >> 6;          // 0..8
    const int g    = wv / 3;
    const int n    = wv % 3;
    const int l31  = lane & 31, l5 = lane >> 5;
    const int p    = blockIdx.x;

    f32x16 acc;
    #pragma unroll
    for (int r = 0; r < 16; ++r) acc[r] = 0.f;

    // slot table: 18 slots of 1KB per stage; slot s -> gate s/6, region byte (s%6)*1024
    const int s0 = wv, s1 = wv + 9;
    const char* W0 = (const char*)((s0 / 6 == 0) ? Wf : ((s0 / 6 == 1) ? Wi : Ws));
    const char* W1 = (const char*)((s1 / 6 == 0) ? Wf : ((s1 / 6 == 1) ? Wi : Ws));
    const char* gp0 = W0 + (size_t)p * 512 * 384 + (s0 % 6) * 1024 + lane * 16;
    const char* gp1 = W1 + (size_t)p * 512 * 384 + (s1 % 6) * 1024 + lane * 16;

    auto stage = [&](int k, int b) {
        char* lb = sm + PJ_STG + b * PJ_SBUF;
        gload16(gp0 + (size_t)k * 6144, lb + s0 * 1024);
        gload16(gp1 + (size_t)k * 6144, lb + s1 * 1024);
    };

    // prologue: issue stage(0) + copy x to LDS; one barrier drains both
    stage(0, 0);
    {
        const unsigned char* wx8 = wsb + WS_X;
        #pragma unroll
        for (int i0 = 0; i0 < 4; ++i0) {
            int i = i0 * NTH + tid;
            if (i < 2048) {
                int row = i >> 6, gq = i & 63;
                *(uint4*)(sm + PJ_X + row * 1040 + gq * 16) =
                    *(const uint4*)(wx8 + row * 1024 + gq * 16);
            }
        }
    }
    __syncthreads();

    // ---- K-loop: 32 chunks of 16c, 2-phase pipeline, 1 barrier/chunk ----
    int cur = 0;
    for (int k = 0; k < 32; ++k) {
        if (k + 1 < 32) stage(k + 1, cur ^ 1);

        const char* wb = sm + PJ_STG + cur * PJ_SBUF + g * 6144 + (n * 32 + l31) * 4
                       + l5 * 8 * 384;
        float w0 = *(const float*)(wb + 0 * 384);
        float w1 = *(const float*)(wb + 1 * 384);
        float w2 = *(const float*)(wb + 2 * 384);
        float w3 = *(const float*)(wb + 3 * 384);
        float w4 = *(const float*)(wb + 4 * 384);
        float w5 = *(const float*)(wb + 5 * 384);
        float w6 = *(const float*)(wb + 6 * 384);
        float w7 = *(const float*)(wb + 7 * 384);
        uint4 bu;
        bu.x = pack2bf(w0, w1);
        bu.y = pack2bf(w2, w3);
        bu.z = pack2bf(w4, w5);
        bu.w = pack2bf(w6, w7);
        short8 a = *(const short8*)(sm + PJ_X + l31 * 1040 + k * 32 + l5 * 16);
        acc = __builtin_amdgcn_mfma_f32_32x32x16_bf16(a, __builtin_bit_cast(short8, bu),
                                                      acc, 0, 0, 0);
        __syncthreads();
        cur ^= 1;
    }

    // ---- add conv partials ----
    const float* part = (const float*)(wsb + WS_PART) + (size_t)p * 9216;
    #pragma unroll
    for (int r = 0; r < 16; ++r) {
        const int b = (r & 3) + 8 * (r >> 2) + 4 * l5;
        acc[r] += part[(g * 32 + b) * 96 + n * 32 + l31];
    }

    // ---- merge + epilogue (x/stage regions dead; reuse sm[0..36864) ) ----
    float* pre = (float*)sm;
    #pragma unroll
    for (int r = 0; r < 16; ++r) {
        const int b = (r & 3) + 8 * (r >> 2) + 4 * l5;
        pre[(g * 32 + b) * 96 + n * 32 + l31] = acc[r];
    }
    __syncthreads();

    #pragma unroll
    for (int j = 0; j < 6; ++j) {
        const int i = j * NTH + tid;
        if (i < 3072) {
            const int b = i / 96, f = i % 96;
            const float gfv = pre[(0 * 32 + b) * 96 + f] + bfp[f];
            const float giv = pre[(1 * 32 + b) * 96 + f] + bip[f];
            const float gsv = pre[(2 * 32 + b) * 96 + f] + bsp[f];
            const size_t idx = ((size_t)b * 512 + p) * 96 + f;
            const float fg = fminf(fmaxf(0.2f * gfv + 0.5f, 0.f), 1.f);
            const float ig = fminf(fmaxf(0.2f * giv + 0.5f, 0.f), 1.f);
            const float sv = fg * s_t[idx] + ig * tanhf(gsv);
            out[idx] = tanhf(sv);
            out[OUT_HALF + idx] = sv;
        }
    }
}

// ================= middle fallback: r6 fused main (ws >= 4.8MB only) =================
constexpr int MX_OFF = 0, MX_STRIDE = 1040;
constexpr int MH_OFF = 33280, MH_BUF = 6656;
constexpr int M_LDS  = MH_OFF + 2 * MH_BUF;   // 46,592

__global__ __launch_bounds__(NTH, 5) void lstm3d_main(
    const float* __restrict__ Wf, const float* __restrict__ Wi, const float* __restrict__ Ws,
    const float* __restrict__ s_t,
    const float* __restrict__ bfp, const float* __restrict__ bip, const float* __restrict__ bsp,
    const unsigned char* __restrict__ wsb, float* __restrict__ out)
{
    extern __shared__ char sm[];
    const int tid  = threadIdx.x;
    const int lane = tid & 63;
    const int wv   = tid >> 6;
    const int g    = wv / 3;
    const int n    = wv % 3;
    const int l31  = lane & 31, l5 = lane >> 5;
    const int p  = blockIdx.x;
    const int dd = p >> 6, hh = (p >> 3) & 7, ww = p & 7;
    const unsigned char* wh8 = wsb + WS_H;
    const unsigned char* wu8 = wsb + WS_U;
    const unsigned char* wx8 = wsb + WS_X;

    f32x16 acc;
    #pragma unroll
    for (int r = 0; r < 16; ++r) acc[r] = 0.f;

    #pragma unroll
    for (int i0 = 0; i0 < 4; ++i0) {
        int i = i0 * NTH + tid;
        if (i < 2048) {
            int row = i >> 6, gq = i & 63;
            *(uint4*)(sm + MX_OFF + row * MX_STRIDE + gq * 16) =
                *(const uint4*)(wx8 + row * 1024 + gq * 16);
        }
    }
    __syncthreads();

    auto do_proj = [&]() {
        const float* Wg = (g == 0) ? Wf : ((g == 1) ? Wi : Ws);
        const float* wbase = Wg + (size_t)p * C_ * F_ + n * 32 + l31;
        float wlA[8], wlB[8], wlC[8];
        auto issue = [&](int ks, float (&wl)[8]) {
            const float* q = wbase + (size_t)(ks * 16 + l5 * 8) * 96;
            #pragma unroll
            for (int j = 0; j < 8; ++j) wl[j] = q[(size_t)j * 96];
        };
        auto step = [&](int ks, float (&wl)[8]) {
            short8 a = *(const short8*)(sm + MX_OFF + l31 * MX_STRIDE + ks * 32 + l5 * 16);
            uint4 bu;
            bu.x = pack2bf(wl[0], wl[1]); bu.y = pack2bf(wl[2], wl[3]);
            bu.z = pack2bf(wl[4], wl[5]); bu.w = pack2bf(wl[6], wl[7]);
            if (ks + 3 < 32) issue(ks + 3, wl);
            acc = __builtin_amdgcn_mfma_f32_32x32x16_bf16(a, __builtin_bit_cast(short8, bu),
                                                          acc, 0, 0, 0);
        };
        issue(0, wlA); issue(1, wlB); issue(2, wlC);
        for (int k3 = 0; k3 < 10; ++k3) {
            step(3 * k3, wlA); step(3 * k3 + 1, wlB); step(3 * k3 + 2, wlC);
        }
        step(30, wlA); step(31, wlB);
    };

    auto do_conv = [&]() {
        const unsigned char* ubrow = wu8 + (size_t)(g * 96 + n * 32 + l31) * 208;
        const int hb = tid / 12, hq = tid % 12;
        auto tapok = [&](int kt, int& np) -> bool {
            int kd = kt / 9, kh = (kt / 3) % 3, kw = kt % 3;
            int nd = dd + kd - 1, nh = hh + kh - 1, nw = ww + kw - 1;
            np = nd * 64 + nh * 8 + nw;
            return ((unsigned)nd < 8u) && ((unsigned)nh < 8u) && ((unsigned)nw < 8u);
        };
        int kt = 0, np = 0;
        while (kt < 27 && !tapok(kt, np)) ++kt;
        if (tid < 384) {
            uint4 hv = *(const uint4*)(wh8 + (size_t)hb * 98304 + np * 192 + hq * 16);
            *(uint4*)(sm + MH_OFF + hb * 208 + hq * 16) = hv;
        }
        __syncthreads();
        int buf = 0;
        while (kt < 27) {
            int ktn = kt + 1, npn = 0;
            while (ktn < 27 && !tapok(ktn, npn)) ++ktn;
            const bool havenext = (ktn < 27);
            uint4 hvn;
            if (havenext && tid < 384)
                hvn = *(const uint4*)(wh8 + (size_t)hb * 98304 + npn * 192 + hq * 16);
            uint4 bb[6];
            const unsigned char* ub = ubrow + (size_t)kt * 59904;
            #pragma unroll
            for (int ks = 0; ks < 6; ++ks)
                bb[ks] = *(const uint4*)(ub + ks * 32 + l5 * 16);
            const char* shb = sm + MH_OFF + buf * MH_BUF;
            #pragma unroll
            for (int ks = 0; ks < 6; ++ks) {
                short8 a = *(const short8*)(shb + l31 * 208 + ks * 32 + l5 * 16);
                short8 b = __builtin_bit_cast(short8, bb[ks]);
                acc = __builtin_amdgcn_mfma_f32_32x32x16_bf16(a, b, acc, 0, 0, 0);
            }
            if (havenext && tid < 384)
                *(uint4*)(sm + MH_OFF + (buf ^ 1) * MH_BUF + hb * 208 + hq * 16) = hvn;
            __syncthreads();
            buf ^= 1;
            kt = ktn;
        }
    };

    if ((blockIdx.x >> 3) & 1) { do_proj(); do_conv(); }
    else                       { do_conv(); do_proj(); }

    __syncthreads();
    float* pre = (float*)sm;
    #pragma unroll
    for (int r = 0; r < 16; ++r) {
        const int b = (r & 3) + 8 * (r >> 2) + 4 * l5;
        pre[(g * 32 + b) * 96 + n * 32 + l31] = acc[r];
    }
    __syncthreads();
    #pragma unroll
    for (int j = 0; j < 6; ++j) {
        const int i = j * NTH + tid;
        if (i < 3072) {
            const int b = i / 96, f = i % 96;
            const float gfv = pre[(0 * 32 + b) * 96 + f] + bfp[f];
            const float giv = pre[(1 * 32 + b) * 96 + f] + bip[f];
            const float gsv = pre[(2 * 32 + b) * 96 + f] + bsp[f];
            const size_t idx = ((size_t)b * 512 + p) * 96 + f;
            const float fg = fminf(fmaxf(0.2f * gfv + 0.5f, 0.f), 1.f);
            const float ig = fminf(fmaxf(0.2f * giv + 0.5f, 0.f), 1.f);
            const float sv = fg * s_t[idx] + ig * tanhf(gsv);
            out[idx] = tanhf(sv);
            out[OUT_HALF + idx] = sv;
        }
    }
}

// ================= fp32 fallback (r2 kernel) =================
constexpr int FNTH = 384;
constexpr int FBPG = 8;
__global__ __launch_bounds__(FNTH, 3) void lstm3d_fused(
    const float* __restrict__ x, const float* __restrict__ h_t, const float* __restrict__ s_t,
    const float* __restrict__ Wf, const float* __restrict__ Wi, const float* __restrict__ Ws,
    const float* __restrict__ Uf, const float* __restrict__ Ui, const float* __restrict__ Us,
    const float* __restrict__ bf, const float* __restrict__ bi, const float* __restrict__ bs,
    float* __restrict__ out)
{
    __shared__ __align__(16) unsigned char lds_raw[B_*C_*2 + B_*F_*4];
    unsigned short* s_in = (unsigned short*)lds_raw;
    float*          s_h  = (float*)(lds_raw + B_*C_*2);
    const int p = blockIdx.x, d = p >> 6, hh = (p >> 3) & 7, ww = p & 7;
    const int tid = threadIdx.x, f = tid % F_, bg = tid / F_, b0 = bg * FBPG;
    {
        const float4* x4 = (const float4*)x;
        ushort4* s4 = (ushort4*)s_in;
        for (int i = tid; i < B_ * C_ / 4; i += FNTH) {
            float4 v = x4[i];
            ushort4 u; u.x = f2bf(v.x); u.y = f2bf(v.y); u.z = f2bf(v.z); u.w = f2bf(v.w);
            s4[i] = u;
        }
    }
    __syncthreads();
    const size_t wbase = (size_t)p * C_ * F_;
    const float* Wfp = Wf + wbase; const float* Wip = Wi + wbase; const float* Wsp = Ws + wbase;
    float af[FBPG], ai[FBPG], as_[FBPG];
    #pragma unroll
    for (int j = 0; j < FBPG; ++j) { af[j] = 0.f; ai[j] = 0.f; as_[j] = 0.f; }
    for (int c = 0; c < C_; c += 4) {
        float xs[FBPG][4];
        #pragma unroll
        for (int j = 0; j < FBPG; ++j) {
            ushort4 uv = *(const ushort4*)&s_in[(b0 + j) * C_ + c];
            xs[j][0] = bf2f(uv.x); xs[j][1] = bf2f(uv.y); xs[j][2] = bf2f(uv.z); xs[j][3] = bf2f(uv.w);
        }
        #pragma unroll
        for (int cc = 0; cc < 4; ++cc) {
            const float wfv = Wfp[(c + cc) * F_ + f], wiv = Wip[(c + cc) * F_ + f], wsv = Wsp[(c + cc) * F_ + f];
            #pragma unroll
            for (int j = 0; j < FBPG; ++j) {
                af[j] = fmaf(xs[j][cc], wfv, af[j]); ai[j] = fmaf(xs[j][cc], wiv, ai[j]); as_[j] = fmaf(xs[j][cc], wsv, as_[j]);
            }
        }
    }
    float cf[FBPG], cig[FBPG], cs[FBPG];
    #pragma unroll
    for (int j = 0; j < FBPG; ++j) { cf[j] = 0.f; cig[j] = 0.f; cs[j] = 0.f; }
    for (int kd = 0; kd < 3; ++kd) {
        const int nd = d + kd - 1; if ((unsigned)nd >= 8u) continue;
        for (int kh = 0; kh < 3; ++kh) {
            const int nh = hh + kh - 1; if ((unsigned)nh >= 8u) continue;
            for (int kw = 0; kw < 3; ++kw) {
                const int nw = ww + kw - 1; if ((unsigned)nw >= 8u) continue;
                const int np = (nd << 6) + (nh << 3) + nw, k = (kd * 3 + kh) * 3 + kw;
                __syncthreads();
                {
                    const float4* h4 = (const float4*)h_t; float4* s4 = (float4*)s_h;
                    for (int i = tid; i < B_ * F_ / 4; i += FNTH) {
                        const int b2 = i / (F_ / 4), r = i % (F_ / 4);
                        s4[i] = h4[(size_t)(b2 * P_ + np) * (F_ / 4) + r];
                    }
                }
                __syncthreads();
                const float* Ufk = Uf + (size_t)k * F_ * F_; const float* Uik = Ui + (size_t)k * F_ * F_; const float* Usk = Us + (size_t)k * F_ * F_;
                for (int ci = 0; ci < F_; ci += 4) {
                    float hs[FBPG][4];
                    #pragma unroll
                    for (int j = 0; j < FBPG; ++j) {
                        float4 t = *(const float4*)&s_h[(b0 + j) * F_ + ci];
                        hs[j][0] = t.x; hs[j][1] = t.y; hs[j][2] = t.z; hs[j][3] = t.w;
                    }
                    #pragma unroll
                    for (int cc = 0; cc < 4; ++cc) {
                        const float ufv = Ufk[(ci + cc) * F_ + f], uiv = Uik[(ci + cc) * F_ + f], usv = Usk[(ci + cc) * F_ + f];
                        #pragma unroll
                        for (int j = 0; j < FBPG; ++j) {
                            cf[j] = fmaf(hs[j][cc], ufv, cf[j]); cig[j] = fmaf(hs[j][cc], uiv, cig[j]); cs[j] = fmaf(hs[j][cc], usv, cs[j]);
                        }
                    }
                }
            }
        }
    }
    const float bfv = bf[f], biv = bi[f], bsv = bs[f];
    #pragma unroll
    for (int j = 0; j < FBPG; ++j) {
        const size_t idx = (size_t)((b0 + j) * P_ + p) * F_ + f;
        const float gf = af[j] + cf[j] + bfv, gi = ai[j] + cig[j] + biv, gs = as_[j] + cs[j] + bsv;
        const float fg = fminf(fmaxf(0.2f * gf + 0.5f, 0.f), 1.f);
        const float ig = fminf(fmaxf(0.2f * gi + 0.5f, 0.f), 1.f);
        const float sv = fg * s_t[idx] + ig * tanhf(gs);
        out[idx] = tanhf(sv);
        out[OUT_HALF + idx] = sv;
    }
}

extern "C" void kernel_launch(void* const* d_in, const int* in_sizes, int n_in,
                              void* d_out, int out_size, void* d_ws, size_t ws_size,
                              hipStream_t stream) {
    const float* x   = (const float*)d_in[0];
    const float* h_t = (const float*)d_in[1];
    const float* s_t = (const float*)d_in[2];
    const float* Wf  = (const float*)d_in[3];
    const float* Wi  = (const float*)d_in[4];
    const float* Ws  = (const float*)d_in[5];
    const float* Uf  = (const float*)d_in[6];
    const float* Ui  = (const float*)d_in[7];
    const float* Us  = (const float*)d_in[8];
    const float* bf  = (const float*)d_in[9];
    const float* bi  = (const float*)d_in[10];
    const float* bs  = (const float*)d_in[11];
    float* out = (float*)d_out;
    unsigned char* wsb = (unsigned char*)d_ws;

    if (ws_size >= WS_END) {
        (void)hipFuncSetAttribute(reinterpret_cast<const void*>(lstm3d_proj),
                                  hipFuncAttributeMaxDynamicSharedMemorySize, PJ_LDS);
        hipLaunchKernelGGL(prep_u, dim3(81), dim3(256), 0, stream, Uf, Ui, Us, wsb);
        hipLaunchKernelGGL(prep_hx, dim3(776), dim3(256), 0, stream, h_t, x, wsb);
        hipLaunchKernelGGL(lstm3d_conv, dim3(P_), dim3(NTH), 0, stream, wsb);
        hipLaunchKernelGGL(lstm3d_proj, dim3(P_), dim3(NTH), PJ_LDS, stream,
                           Wf, Wi, Ws, s_t, bf, bi, bs, wsb, out);
    } else if (ws_size >= WS_PART) {
        (void)hipFuncSetAttribute(reinterpret_cast<const void*>(lstm3d_main),
                                  hipFuncAttributeMaxDynamicSharedMemorySize, M_LDS);
        hipLaunchKernelGGL(prep_u, dim3(81), dim3(256), 0, stream, Uf, Ui, Us, wsb);
        hipLaunchKernelGGL(prep_hx, dim3(776), dim3(256), 0, stream, h_t, x, wsb);
        hipLaunchKernelGGL(lstm3d_main, dim3(P_), dim3(NTH), M_LDS, stream,
                           Wf, Wi, Ws, s_t, bf, bi, bs, wsb, out);
    } else {
        hipLaunchKernelGGL(lstm3d_fused, dim3(P_), dim3(FNTH), 0, stream,
                           x, h_t, s_t, Wf, Wi, Ws, Uf, Ui, Us, bf, bi, bs, out);
    }
}